// Round 10
// baseline (98.369 us; speedup 1.0000x reference)
//
#include <hip/hip_runtime.h>
#include <hip/hip_bf16.h>
#include <math.h>

#define B_DIM 8
#define T_DIM 1024
#define D_DIM 512
#define BT (B_DIM * T_DIM)     // 8192
#define NTILES 512             // 8 batches x 64 tiles of 16 queries
#define WPT 8                  // waves per tile (k-split)
#define NWAVES (NTILES * WPT)  // 4096
#define PART_STRIDE 1280       // 5 tiles * 256 entries
#define SS_STRIDE 96           // 6 slots * 16 rows

typedef __bf16 bf16x8 __attribute__((ext_vector_type(8)));
typedef float floatx4 __attribute__((ext_vector_type(4)));

__device__ __forceinline__ float wave_reduce_sum(float v) {
#pragma unroll
    for (int off = 32; off > 0; off >>= 1) v += __shfl_xor(v, off, 64);
    return v;
}

// fast stable softplus: max(y,0) + log(1 + exp(-|y|)); arg of log in (1,2]
__device__ __forceinline__ float softplus(float y) {
    return fmaxf(y, 0.0f) + __logf(1.0f + __expf(-fabsf(y)));
}

// 8 fp32 -> bf16x8 fragment, RNE (validated rounds 7-9)
__device__ __forceinline__ bf16x8 cvt8(float4 x, float4 y) {
    union { ushort u[8]; bf16x8 v; } r;
    __hip_bfloat162 h0 = __float22bfloat162_rn(make_float2(x.x, x.y));
    __hip_bfloat162 h1 = __float22bfloat162_rn(make_float2(x.z, x.w));
    __hip_bfloat162 h2 = __float22bfloat162_rn(make_float2(y.x, y.y));
    __hip_bfloat162 h3 = __float22bfloat162_rn(make_float2(y.z, y.w));
    ushort2 p0 = *(ushort2*)&h0, p1 = *(ushort2*)&h1;
    ushort2 p2 = *(ushort2*)&h2, p3 = *(ushort2*)&h3;
    r.u[0] = p0.x; r.u[1] = p0.y; r.u[2] = p1.x; r.u[3] = p1.y;
    r.u[4] = p2.x; r.u[5] = p2.y; r.u[6] = p3.x; r.u[7] = p3.y;
    return r.v;
}

// ---------------- Phase 1: barrier-free streaming band GEMM ----------------
// Wave wg: tile = wg/8 -> (b, t0); k-slice w = wg%8 (64 elems). Computes the
// 5 cross tiles (R9-validated): q -> (ti,tj): 0:(1,0) 1:(1,1) 2:(1,2) 3:(0,1)
// 4:(2,1) of S[u][v] = m_{t0-16+u} . a_{t0-16+v}. Writes per-wave partial
// accumulators + per-row sumsq partials to ws. NO LDS, NO barriers.
__global__ __launch_bounds__(256, 4) void band2_kernel(
    const float* __restrict__ m, const float* __restrict__ a,
    float* __restrict__ part, float* __restrict__ ssbuf)
{
    int wg   = blockIdx.x * 4 + (threadIdx.x >> 6);  // global wave [0, 4096)
    int tile = wg >> 3;
    int w    = wg & 7;
    int b    = tile >> 6;
    int t0   = (tile & 63) << 4;
    int lane = threadIdx.x & 63;
    int mrow = lane & 15;
    int kgrp = lane >> 4;
    int koff = w * 64 + kgrp * 8;

    const float* mb = m + ((size_t)b << 19);   // b*1024*512
    const float* ab = a + ((size_t)b << 19);

    const float* mp[3]; const float* ap[3];
#pragma unroll
    for (int s = 0; s < 3; ++s) {
        int r = t0 - 16 + s * 16 + mrow;       // clamped; masked in epilogue
        r = min(max(r, 0), T_DIM - 1);
        mp[s] = mb + (size_t)r * D_DIM + koff;
        ap[s] = ab + (size_t)r * D_DIM + koff;
    }

    floatx4 acc[5];
#pragma unroll
    for (int q = 0; q < 5; ++q) acc[q] = (floatx4){0.f,0.f,0.f,0.f};
    float ssm[3] = {0.f,0.f,0.f}, ssa[3] = {0.f,0.f,0.f};

#pragma unroll
    for (int ks = 0; ks < 2; ++ks) {           // 2 k-chunks of 32
        bf16x8 am[3], av[3];
#pragma unroll
        for (int s = 0; s < 3; ++s) {
            float4 x = *(const float4*)(mp[s] + ks * 32);
            float4 y = *(const float4*)(mp[s] + ks * 32 + 4);
            ssm[s] += x.x*x.x + x.y*x.y + x.z*x.z + x.w*x.w
                    + y.x*y.x + y.y*y.y + y.z*y.z + y.w*y.w;
            am[s] = cvt8(x, y);
            float4 u = *(const float4*)(ap[s] + ks * 32);
            float4 v = *(const float4*)(ap[s] + ks * 32 + 4);
            ssa[s] += u.x*u.x + u.y*u.y + u.z*u.z + u.w*u.w
                    + v.x*v.x + v.y*v.y + v.z*v.z + v.w*v.w;
            av[s] = cvt8(u, v);
        }
        acc[0] = __builtin_amdgcn_mfma_f32_16x16x32_bf16(am[1], av[0], acc[0], 0, 0, 0);
        acc[1] = __builtin_amdgcn_mfma_f32_16x16x32_bf16(am[1], av[1], acc[1], 0, 0, 0);
        acc[2] = __builtin_amdgcn_mfma_f32_16x16x32_bf16(am[1], av[2], acc[2], 0, 0, 0);
        acc[3] = __builtin_amdgcn_mfma_f32_16x16x32_bf16(am[0], av[1], acc[3], 0, 0, 0);
        acc[4] = __builtin_amdgcn_mfma_f32_16x16x32_bf16(am[2], av[1], acc[4], 0, 0, 0);
    }

    // sumsq: reduce across the 4 kgrp lanes of each row (xor 16, 32)
#pragma unroll
    for (int off = 16; off <= 32; off <<= 1) {
#pragma unroll
        for (int s = 0; s < 3; ++s) {
            ssm[s] += __shfl_xor(ssm[s], off, 64);
            ssa[s] += __shfl_xor(ssa[s], off, 64);
        }
    }
    if (kgrp == 0) {
        float* sw = ssbuf + (size_t)wg * SS_STRIDE;
#pragma unroll
        for (int s = 0; s < 3; ++s) {
            sw[s * 16 + mrow]       = ssm[s];   // slots 0-2: m rows
            sw[(3 + s) * 16 + mrow] = ssa[s];   // slots 3-5: a rows
        }
    }
    // score partials. C layout: col = lane&15, row = (lane>>4)*4 + reg
    // entry = q*256 + row*16 + col -> coalesced 64B chunks per store inst.
    float* pw = part + (size_t)wg * PART_STRIDE;
#pragma unroll
    for (int q = 0; q < 5; ++q)
#pragma unroll
        for (int r = 0; r < 4; ++r)
            pw[q * 256 + (kgrp * 4 + r) * 16 + mrow] = acc[q][r];
}

// ---------------- Phase 2: combine partials + fused loss epilogue ----------
// Epilogue logic identical to validated round 7 (both directions per thread).
__global__ __launch_bounds__(256) void epi_kernel(
    const float* __restrict__ part, const float* __restrict__ ssbuf,
    const float* __restrict__ pscale, const float* __restrict__ pbias,
    float* __restrict__ part_loss, float* __restrict__ part_corr)
{
    __shared__ float Sbuf[48][49];
    __shared__ float norms[6][16];
    __shared__ float rowpos[16], colpos[16], shl[4];

    int tile = blockIdx.x;
    int t0   = (tile & 63) << 4;
    int tid  = threadIdx.x;
    int w    = tid >> 6;
    int lane = tid & 63;

    float scale = expf(pscale[0]), bias = pbias[0];

    const float* pbase = part + (size_t)tile * WPT * PART_STRIDE;
    const int tu[5] = {16, 16, 16, 0, 32};
    const int tv[5] = {0, 16, 32, 16, 16};
#pragma unroll
    for (int j = 0; j < 5; ++j) {
        int e = tid + j * 256;
        float s = 0.f;
#pragma unroll
        for (int wgi = 0; wgi < WPT; ++wgi)
            s += pbase[wgi * PART_STRIDE + e];
        int q = e >> 8, r2 = e & 255;
        Sbuf[tu[q] + (r2 >> 4)][tv[q] + (r2 & 15)] = s;
    }
    if (tid < 96) {
        const float* sbase = ssbuf + (size_t)tile * WPT * SS_STRIDE;
        float ss = 0.f;
#pragma unroll
        for (int wgi = 0; wgi < WPT; ++wgi)
            ss += sbase[wgi * SS_STRIDE + tid];
        norms[tid >> 4][tid & 15] = 1.0f / fmaxf(sqrtf(ss), 1e-12f);
    }
    __syncthreads();

    // ---- epilogue (masks/keys identical to validated round 7) ----
    int i = tid >> 4, cc = tid & 15;
    float loss = 0.0f;

    {   // m2a: query t = t0+i (row u = 16+i), cols v = tj*16+cc
        float im_u = norms[1][i];
        float mmax = -1e30f, mpos = 0.0f;
#pragma unroll
        for (int tj = 0; tj < 3; ++tj) {
            int v  = tj * 16 + cc;
            int dd = v - i;                    // c - t + 16
            int c  = t0 - 16 + v;
            if (dd >= 0 && dd < 32 && c >= 0 && c < T_DIM) {
                float sv = Sbuf[16 + i][v] * norms[3 + tj][cc];  // s*inva[c]
                float logit = sv * im_u * scale + bias;
                bool pos = (dd >= 12) && (dd <= 19);
                loss += softplus(pos ? -logit : logit);
                if (sv > mmax) { mmax = sv; mpos = pos ? 1.0f : 0.0f; }
            }
        }
#pragma unroll
        for (int off = 1; off < 16; off <<= 1) {
            float ov = __shfl_xor(mmax, off, 64);
            float op = __shfl_xor(mpos, off, 64);
            if (ov > mmax) { mmax = ov; mpos = op; }
        }
        if (cc == 0) rowpos[i] = mpos;
    }
    {   // a2m: query t = t0+i (col v = 16+i), rows u2 = tj*16+cc
        float ia_v = norms[4][i];
        float amax = -1e30f, apos = 0.0f;
#pragma unroll
        for (int tj = 0; tj < 3; ++tj) {
            int u2 = tj * 16 + cc;
            int ee = u2 - i;                   // r - t + 16
            int r  = t0 - 16 + u2;
            if (ee >= 0 && ee < 32 && r >= 0 && r < T_DIM) {
                float sv = Sbuf[u2][16 + i] * norms[tj][cc];     // s*invm[r]
                float logit = sv * ia_v * scale + bias;
                bool pos = (ee >= 12) && (ee <= 19);
                loss += softplus(pos ? -logit : logit);
                if (sv > amax) { amax = sv; apos = pos ? 1.0f : 0.0f; }
            }
        }
#pragma unroll
        for (int off = 1; off < 16; off <<= 1) {
            float ov = __shfl_xor(amax, off, 64);
            float op = __shfl_xor(apos, off, 64);
            if (ov > amax) { amax = ov; apos = op; }
        }
        if (cc == 0) colpos[i] = apos;
    }

    loss = wave_reduce_sum(loss);
    if (lane == 0) shl[w] = loss;
    __syncthreads();
    if (tid == 0) {
        float C = 0.0f;
#pragma unroll
        for (int r = 0; r < 16; ++r) C += rowpos[r] + colpos[r];
        part_loss[tile] = shl[0] + shl[1] + shl[2] + shl[3];
        part_corr[tile] = C;
    }
}

__global__ __launch_bounds__(256) void finalsum_kernel(
    const float* __restrict__ part_loss, const float* __restrict__ part_corr,
    float* __restrict__ out)
{
    int tid = threadIdx.x;
    float l = part_loss[tid] + part_loss[tid + 256];
    float c = part_corr[tid] + part_corr[tid + 256];
    l = wave_reduce_sum(l);
    c = wave_reduce_sum(c);
    __shared__ float shl[4], shc[4];
    int w = tid >> 6, lane = tid & 63;
    if (lane == 0) { shl[w] = l; shc[w] = c; }
    __syncthreads();
    if (tid == 0) {
        out[0] = (shl[0] + shl[1] + shl[2] + shl[3]) / 16384.0f;
        out[1] = (shc[0] + shc[1] + shc[2] + shc[3]) / 16384.0f;
    }
}

extern "C" void kernel_launch(void* const* d_in, const int* in_sizes, int n_in,
                              void* d_out, int out_size, void* d_ws, size_t ws_size,
                              hipStream_t stream)
{
    const float* m  = (const float*)d_in[0];
    const float* a  = (const float*)d_in[1];
    const float* ps = (const float*)d_in[2];
    const float* pb = (const float*)d_in[3];
    float* out = (float*)d_out;

    float* part      = (float*)d_ws;                        // 4096*1280
    float* ssbuf     = part + (size_t)NWAVES * PART_STRIDE; // 4096*96
    float* part_loss = ssbuf + (size_t)NWAVES * SS_STRIDE;  // 512
    float* part_corr = part_loss + NTILES;                  // 512

    band2_kernel<<<NWAVES / 4, 256, 0, stream>>>(m, a, part, ssbuf);
    epi_kernel<<<NTILES, 256, 0, stream>>>(part, ssbuf, ps, pb,
                                           part_loss, part_corr);
    finalsum_kernel<<<1, 256, 0, stream>>>(part_loss, part_corr, out);
}

// Round 11
// 91.813 us; speedup vs baseline: 1.0714x; 1.0714x over previous
//
#include <hip/hip_runtime.h>
#include <math.h>

#define B_DIM 8
#define T_DIM 1024
#define D_DIM 512
#define BT (B_DIM * T_DIM)   // 8192
#define NBLK 512             // 8 batches x 64 tiles of 16 queries

typedef __bf16 bf16x8 __attribute__((ext_vector_type(8)));
typedef float floatx4 __attribute__((ext_vector_type(4)));

__device__ __forceinline__ float wave_reduce_sum(float v) {
#pragma unroll
    for (int off = 32; off > 0; off >>= 1) v += __shfl_xor(v, off, 64);
    return v;
}

// fp32 -> bf16 round-to-nearest-even (validated rounds 1-5)
__device__ __forceinline__ ushort f2bf(float x) {
    unsigned u = __float_as_uint(x);
    return (ushort)((u + 0x7fffu + ((u >> 16) & 1u)) >> 16);
}

__device__ __forceinline__ float softplus(float y) {
    return fmaxf(y, 0.0f) + log1pf(expf(-fabsf(y)));
}

// ---------------- Phase 1: normalize + convert to bf16 (R2-validated) ------
// XCD swizzle: rows of batch b are written by blocks with blockIdx%8 == b so
// each XCD's L2 ends up holding its own batch's mhat/ahat (4 MB).
__global__ __launch_bounds__(256) void prep_kernel(
    const float* __restrict__ m, const float* __restrict__ a,
    ushort* __restrict__ mhat, ushort* __restrict__ ahat)
{
    int blk = blockIdx.x;                              // [0, 2048)
    int wid = (blk & 7) * 1024 + (blk >> 3) * 4 + (threadIdx.x >> 6);
    int lane = threadIdx.x & 63;
    const float4* mr = (const float4*)(m + (size_t)wid * D_DIM);
    const float4* ar = (const float4*)(a + (size_t)wid * D_DIM);
    float4 m0 = mr[lane], m1 = mr[lane + 64];
    float4 a0 = ar[lane], a1 = ar[lane + 64];
    float sm = m0.x*m0.x + m0.y*m0.y + m0.z*m0.z + m0.w*m0.w
             + m1.x*m1.x + m1.y*m1.y + m1.z*m1.z + m1.w*m1.w;
    float sa = a0.x*a0.x + a0.y*a0.y + a0.z*a0.z + a0.w*a0.w
             + a1.x*a1.x + a1.y*a1.y + a1.z*a1.z + a1.w*a1.w;
    sm = wave_reduce_sum(sm);
    sa = wave_reduce_sum(sa);
    float im = 1.0f / fmaxf(sqrtf(sm), 1e-12f);
    float ia = 1.0f / fmaxf(sqrtf(sa), 1e-12f);
    ushort4 mo0 = { f2bf(m0.x*im), f2bf(m0.y*im), f2bf(m0.z*im), f2bf(m0.w*im) };
    ushort4 mo1 = { f2bf(m1.x*im), f2bf(m1.y*im), f2bf(m1.z*im), f2bf(m1.w*im) };
    ushort4 ao0 = { f2bf(a0.x*ia), f2bf(a0.y*ia), f2bf(a0.z*ia), f2bf(a0.w*ia) };
    ushort4 ao1 = { f2bf(a1.x*ia), f2bf(a1.y*ia), f2bf(a1.z*ia), f2bf(a1.w*ia) };
    ushort4* mw = (ushort4*)(mhat + (size_t)wid * D_DIM);
    ushort4* aw = (ushort4*)(ahat + (size_t)wid * D_DIM);
    mw[lane] = mo0; mw[lane + 64] = mo1;
    aw[lane] = ao0; aw[lane + 64] = ao1;
}

// ---------------- Phase 2: bf16 cross-band + fused loss (R9 structure) -----
// Block -> (b = blk%8, t0 = (blk/8)*16): XCD b reads only batch b (L2-hot).
// 5 cross tiles of S[u][v] = mhat_{t0-16+u} . ahat_{t0-16+v}:
//   q -> (ti,tj): 0:(1,0) 1:(1,1) 2:(1,2) 3:(0,1) 4:(2,1)
// Rows normalized, so S is the logit input and the argmax key directly.
__global__ __launch_bounds__(256) void crossband_kernel(
    const ushort* __restrict__ mhat, const ushort* __restrict__ ahat,
    const float* __restrict__ pscale, const float* __restrict__ pbias,
    float* __restrict__ part_loss, float* __restrict__ part_corr)
{
    __shared__ float red[4][5][272];   // k-split score partials (stride 17)
    __shared__ float Sbuf[48][49];     // combined scores (cross region used)
    __shared__ float rowpos[16], colpos[16], shl[4];

    int blk = blockIdx.x;
    int b   = blk & 7;
    int t0  = (blk >> 3) << 4;
    int tid  = threadIdx.x;
    int w    = tid >> 6;               // wave id: k-split (128 elems each)
    int lane = tid & 63;
    int mrow = lane & 15;
    int kgrp = lane >> 4;
    int koff = w * 128 + kgrp * 8;

    const ushort* mb = mhat + ((size_t)b << 19);   // b*1024*512
    const ushort* ab = ahat + ((size_t)b << 19);

    const ushort* mp[3]; const ushort* ap[3];
#pragma unroll
    for (int s = 0; s < 3; ++s) {
        int r = t0 - 16 + s * 16 + mrow;       // clamped; masked in epilogue
        r = min(max(r, 0), T_DIM - 1);
        mp[s] = mb + (size_t)r * D_DIM + koff;
        ap[s] = ab + (size_t)r * D_DIM + koff;
    }

    floatx4 acc[5];
#pragma unroll
    for (int q = 0; q < 5; ++q) acc[q] = (floatx4){0.f,0.f,0.f,0.f};

#pragma unroll
    for (int ks = 0; ks < 4; ++ks) {           // 4 k-chunks of 32
        bf16x8 am[3], av[3];
#pragma unroll
        for (int s = 0; s < 3; ++s) {
            am[s] = *(const bf16x8*)(mp[s] + ks * 32);
            av[s] = *(const bf16x8*)(ap[s] + ks * 32);
        }
        acc[0] = __builtin_amdgcn_mfma_f32_16x16x32_bf16(am[1], av[0], acc[0], 0, 0, 0);
        acc[1] = __builtin_amdgcn_mfma_f32_16x16x32_bf16(am[1], av[1], acc[1], 0, 0, 0);
        acc[2] = __builtin_amdgcn_mfma_f32_16x16x32_bf16(am[1], av[2], acc[2], 0, 0, 0);
        acc[3] = __builtin_amdgcn_mfma_f32_16x16x32_bf16(am[0], av[1], acc[3], 0, 0, 0);
        acc[4] = __builtin_amdgcn_mfma_f32_16x16x32_bf16(am[2], av[1], acc[4], 0, 0, 0);
    }

    // k-split score partials. C layout: col=lane&15, row=(lane>>4)*4+reg
#pragma unroll
    for (int q = 0; q < 5; ++q)
#pragma unroll
        for (int r = 0; r < 4; ++r)
            red[w][q][(kgrp * 4 + r) * 17 + mrow] = acc[q][r];
    __syncthreads();

    // combine 4 k-partials -> Sbuf (5 tiles x 256 entries, 5 per thread)
    {
        const int tu[5] = {16, 16, 16, 0, 32};
        const int tv[5] = {0, 16, 32, 16, 16};
#pragma unroll
        for (int j = 0; j < 5; ++j) {
            int e = tid + j * 256;
            int q = e >> 8, r2 = e & 255;
            int rho = r2 >> 4, kap = r2 & 15;
            float s4 = red[0][q][rho * 17 + kap] + red[1][q][rho * 17 + kap]
                     + red[2][q][rho * 17 + kap] + red[3][q][rho * 17 + kap];
            Sbuf[tu[q] + rho][tv[q] + kap] = s4;
        }
    }
    __syncthreads();

    // ---- epilogue (masks identical to validated rounds 7/9) ----
    float scale = expf(pscale[0]), bias = pbias[0];
    int i = tid >> 4, cc = tid & 15;
    float loss = 0.0f;

    {   // m2a: query t = t0+i (row u = 16+i), cols v = tj*16+cc
        float mmax = -1e30f, mpos = 0.0f;
#pragma unroll
        for (int tj = 0; tj < 3; ++tj) {
            int v  = tj * 16 + cc;
            int dd = v - i;                    // c - t + 16
            int c  = t0 - 16 + v;
            if (dd >= 0 && dd < 32 && c >= 0 && c < T_DIM) {
                float sv = Sbuf[16 + i][v];
                float logit = sv * scale + bias;
                bool pos = (dd >= 12) && (dd <= 19);
                loss += softplus(pos ? -logit : logit);
                if (sv > mmax) { mmax = sv; mpos = pos ? 1.0f : 0.0f; }
            }
        }
#pragma unroll
        for (int off = 1; off < 16; off <<= 1) {
            float ov = __shfl_xor(mmax, off, 64);
            float op = __shfl_xor(mpos, off, 64);
            if (ov > mmax) { mmax = ov; mpos = op; }
        }
        if (cc == 0) rowpos[i] = mpos;
    }
    {   // a2m: query t = t0+i (col v = 16+i), rows u2 = tj*16+cc
        float amax = -1e30f, apos = 0.0f;
#pragma unroll
        for (int tj = 0; tj < 3; ++tj) {
            int u2 = tj * 16 + cc;
            int ee = u2 - i;                   // r - t + 16
            int r  = t0 - 16 + u2;
            if (ee >= 0 && ee < 32 && r >= 0 && r < T_DIM) {
                float sv = Sbuf[u2][16 + i];
                float logit = sv * scale + bias;
                bool pos = (ee >= 12) && (ee <= 19);
                loss += softplus(pos ? -logit : logit);
                if (sv > amax) { amax = sv; apos = pos ? 1.0f : 0.0f; }
            }
        }
#pragma unroll
        for (int off = 1; off < 16; off <<= 1) {
            float ov = __shfl_xor(amax, off, 64);
            float op = __shfl_xor(apos, off, 64);
            if (ov > amax) { amax = ov; apos = op; }
        }
        if (cc == 0) colpos[i] = apos;
    }

    loss = wave_reduce_sum(loss);
    if (lane == 0) shl[w] = loss;
    __syncthreads();
    if (tid == 0) {
        float C = 0.0f;
#pragma unroll
        for (int r = 0; r < 16; ++r) C += rowpos[r] + colpos[r];
        part_loss[blk] = shl[0] + shl[1] + shl[2] + shl[3];
        part_corr[blk] = C;
    }
}

__global__ __launch_bounds__(256) void finalsum_kernel(
    const float* __restrict__ part_loss, const float* __restrict__ part_corr,
    float* __restrict__ out)
{
    int tid = threadIdx.x;
    float l = part_loss[tid] + part_loss[tid + 256];
    float c = part_corr[tid] + part_corr[tid + 256];
    l = wave_reduce_sum(l);
    c = wave_reduce_sum(c);
    __shared__ float shl[4], shc[4];
    int w = tid >> 6, lane = tid & 63;
    if (lane == 0) { shl[w] = l; shc[w] = c; }
    __syncthreads();
    if (tid == 0) {
        out[0] = (shl[0] + shl[1] + shl[2] + shl[3]) / 16384.0f;
        out[1] = (shc[0] + shc[1] + shc[2] + shc[3]) / 16384.0f;
    }
}

extern "C" void kernel_launch(void* const* d_in, const int* in_sizes, int n_in,
                              void* d_out, int out_size, void* d_ws, size_t ws_size,
                              hipStream_t stream)
{
    const float* m  = (const float*)d_in[0];
    const float* a  = (const float*)d_in[1];
    const float* ps = (const float*)d_in[2];
    const float* pb = (const float*)d_in[3];
    float* out = (float*)d_out;

    const size_t MHAT_ELEMS = (size_t)BT * D_DIM;      // ushorts
    ushort* mhat = (ushort*)d_ws;
    ushort* ahat = mhat + MHAT_ELEMS;
    float*  part_loss = (float*)(ahat + MHAT_ELEMS);   // 512
    float*  part_corr = part_loss + NBLK;              // 512

    prep_kernel<<<BT / 4, 256, 0, stream>>>(m, a, mhat, ahat);
    crossband_kernel<<<NBLK, 256, 0, stream>>>(mhat, ahat, ps, pb,
                                               part_loss, part_corr);
    finalsum_kernel<<<1, 256, 0, stream>>>(part_loss, part_corr, out);
}